// Round 11
// baseline (619.827 us; speedup 1.0000x reference)
//
#include <hip/hip_runtime.h>
#include <stdint.h>

typedef __attribute__((ext_vector_type(4))) float floatx4;
typedef __attribute__((ext_vector_type(8))) short short8;
typedef unsigned short ushort_t;

#define DEVI __device__ __forceinline__

// Problem constants
constexpr int Bc   = 4;
constexpr int Sc   = 1024;
constexpr int Hc   = 4096;
constexpr int NHc  = 32;
constexpr int NKVc = 8;
constexpr int Dc   = 128;
constexpr int QKVO = 6144;           // NH*D + 2*NKV*D
constexpr int Mc   = Bc * Sc;        // 4096 tokens

DEVI ushort_t f2bf(float f) {
  union { float f; unsigned u; } x; x.f = f;
  unsigned u = x.u;
  u += 0x7fffu + ((u >> 16) & 1u);   // RNE
  return (ushort_t)(u >> 16);
}

DEVI short8 cvt8(floatx4 a, floatx4 b) {
  short8 r;
  r[0] = (short)f2bf(a[0]); r[1] = (short)f2bf(a[1]);
  r[2] = (short)f2bf(a[2]); r[3] = (short)f2bf(a[3]);
  r[4] = (short)f2bf(b[0]); r[5] = (short)f2bf(b[1]);
  r[6] = (short)f2bf(b[2]); r[7] = (short)f2bf(b[3]);
  return r;
}

DEVI void load_lds16(const ushort_t* g, ushort_t* l) {
  __builtin_amdgcn_global_load_lds(
      (const __attribute__((address_space(1))) void*)g,
      (__attribute__((address_space(3))) void*)l, 16, 0, 0);
}

#define BARRIER()  asm volatile("s_barrier" ::: "memory")
#define LGKM0()    asm volatile("s_waitcnt lgkmcnt(0)" ::: "memory")
#define VMCNT(n)   asm volatile("s_waitcnt vmcnt(" #n ")" ::: "memory")

// ---------------------------------------------------------------------------
// f32 -> bf16 plain convert (8 elems/thread)
// ---------------------------------------------------------------------------
__global__ __launch_bounds__(256)
void cvt_bf16(const float* __restrict__ src, ushort_t* __restrict__ dst, int n8)
{
  const int i = blockIdx.x * 256 + threadIdx.x;
  if (i >= n8) return;
  const floatx4 f0 = *(const floatx4*)(src + (size_t)i * 8);
  const floatx4 f1 = *(const floatx4*)(src + (size_t)i * 8 + 4);
  *(short8*)(dst + (size_t)i * 8) = cvt8(f0, f1);
}

// ---------------------------------------------------------------------------
// transpose + convert: src[R][C] f32 -> dst[C][R] bf16.  64x64 tiles.
// ---------------------------------------------------------------------------
__global__ __launch_bounds__(256)
void transpose_cvt(const float* __restrict__ src, ushort_t* __restrict__ dst,
                   int R, int C)
{
  __shared__ float ts[64][67];
  const int cb = C >> 6;
  const int r0 = (blockIdx.x / cb) << 6;
  const int c0 = (blockIdx.x % cb) << 6;
  const int t  = threadIdx.x;

  const int lr = t >> 4, lc = (t & 15) << 2;
#pragma unroll
  for (int i = 0; i < 4; ++i) {
    const floatx4 v = *(const floatx4*)(src + (size_t)(r0 + lr + 16 * i) * C + c0 + lc);
#pragma unroll
    for (int j = 0; j < 4; ++j) ts[lr + 16 * i][lc + j] = v[j];
  }
  __syncthreads();

  const int c     = ((t >> 6) << 4) + ((t & 63) >> 2);
  const int chunk = t & 3;
  short8 t0, t1;
#pragma unroll
  for (int k = 0; k < 8; ++k) t0[k] = (short)f2bf(ts[chunk * 16 + k][c]);
#pragma unroll
  for (int k = 0; k < 8; ++k) t1[k] = (short)f2bf(ts[chunk * 16 + 8 + k][c]);
  ushort_t* dp = dst + (size_t)(c0 + c) * R + r0 + chunk * 16;
  *(short8*)dp       = t0;
  *(short8*)(dp + 8) = t1;
}

// ---------------------------------------------------------------------------
// V transpose (bf16 -> bf16): qkv[b][s][5120 + hkv*128 + d] -> vt[b][hkv][d][s]
// ---------------------------------------------------------------------------
__global__ __launch_bounds__(256)
void v_transpose(const ushort_t* __restrict__ qkv, ushort_t* __restrict__ vt)
{
  __shared__ ushort_t ts[64][72];
  const int bid = blockIdx.x;
  const int db  = bid & 1;
  const int sb  = (bid >> 1) & 15;
  const int hkv = (bid >> 5) & 7;
  const int b   = bid >> 8;
  const int t   = threadIdx.x;

  const ushort_t* src = qkv + (size_t)(b * Sc + sb * 64) * QKVO
                        + (NHc * Dc + NKVc * Dc) + hkv * Dc + db * 64;
  const int lr = t >> 3, lc = (t & 7) * 8;
  *(short8*)&ts[lr][lc]      = *(const short8*)(src + (size_t)lr * QKVO + lc);
  *(short8*)&ts[lr + 32][lc] = *(const short8*)(src + (size_t)(lr + 32) * QKVO + lc);
  __syncthreads();

  ushort_t* dst = vt + ((size_t)(b * NKVc + hkv) * Dc + db * 64) * Sc + sb * 64;
  const int dr  = t >> 2;
  const int sc0 = (t & 3) * 16;
  short8 o0, o1;
#pragma unroll
  for (int k = 0; k < 8; ++k) o0[k] = (short)ts[sc0 + k][dr];
#pragma unroll
  for (int k = 0; k < 8; ++k) o1[k] = (short)ts[sc0 + 8 + k][dr];
  *(short8*)(dst + (size_t)dr * Sc + sc0)     = o0;
  *(short8*)(dst + (size_t)dr * Sc + sc0 + 8) = o1;
}

// ---------------------------------------------------------------------------
// 256 x (64*NFRAG) deep-pipeline GEMM.  Iter = 2 K-tiles (T0->slot0, T1->slot1,
// static).  8 phases/iter, tiles interleaved: (t0,lo,ks0)(t1,lo,ks0)(t0,hi,ks0)
// (t1,hi,ks0)(t0,lo,ks1)(t1,lo,ks1)(t0,hi,ks1)(t1,hi,ks1).
// A parts = frag quadrants: Aq0 rows {0,128}, Aq1 rows {64,192} (each 2 loads).
// B read FULLY at its tile's first phase (both ks -> regs) so B LDS frees
// immediately; B[t] staged 2 phases, depth 5-7.
// Stage map: ph1: Aq1[t1] | ph2,3: B[t2] | ph4,5: B[t3] | ph6: Aq0[t2]
//            | ph7: Aq0[t3] | ph8: Aq1[t2].   (2 loads/thread/phase)
// Forces: vmcnt(4) end-ph1 (covers <=prev-ph7: Aq0[t1],B[t1]); vmcnt(4)
// end-ph2 (<=prev-ph8: Aq1[t0]); vmcnt(4|3) end-ph3 (<=ph1: Aq1[t1]);
// vmcnt(4) end-ph8 (<=ph6: Aq0[t2]+B[t2]).  Never drains mid-loop.
// ---------------------------------------------------------------------------
template<int NFRAG, bool OBF16>
__global__ __launch_bounds__(512, 2)
void gemm_nt8d(const ushort_t* __restrict__ A, const ushort_t* __restrict__ BT,
               void* __restrict__ Cp, int M, int N, int K)
{
  constexpr int BN = 64 * NFRAG;
  __shared__ __align__(16) ushort_t As[2][256 * 64];
  __shared__ __align__(16) ushort_t Bs[2][BN * 64];

  const int nb  = N / BN;
  const int nwg = (M >> 8) * nb;
  int bid = blockIdx.x;
  bid = (bid & 7) * (nwg >> 3) + (bid >> 3);     // XCD swizzle (nwg%8==0)
  const int bm = bid / nb, bn = bid % nb;
  const int m0 = bm << 8, n0 = bn * BN;

  const int tid  = threadIdx.x;
  const int wid  = tid >> 6, lane = tid & 63;
  const int wm   = wid >> 2, wn = wid & 3;       // wave grid 2x4
  const int fr   = lane & 15;
  const int g16  = (lane >> 4) << 4;             // frag k byte base
  const int rsw  = (fr & 7) << 4;                // read-side XOR
  const int l8   = lane >> 3;
  const int scol = ((lane & 7) ^ l8) << 3;       // pre-swizzled src col (ushorts)

  const int sr   = (wid << 3);                   // wave staging row base
  const size_t Ks = (size_t)K;
  const ushort_t* agS = A  + (size_t)(m0 + sr + l8) * K + scol;
  const ushort_t* bgS = BT + (size_t)(n0 + sr + l8) * K + scol;

  const int rowA = (wm * 128 + fr) * 128;        // byte base for A frag reads
  const int rowB = (wn * 16 * NFRAG + fr) * 128;
  const int cb0  = g16 ^ rsw;
  const int cb1  = (64 + g16) ^ rsw;

  const floatx4 fz = {0.f, 0.f, 0.f, 0.f};
  floatx4 acc[8][NFRAG];
#pragma unroll
  for (int i = 0; i < 8; ++i)
#pragma unroll
    for (int f = 0; f < NFRAG; ++f) acc[i][f] = fz;

  // stage helpers (2 loads each except SB2 at NFRAG==3)
  auto SAq0 = [&](int s, size_t kn) {            // frag rows 0-3 of both wave-halves
    load_lds16(agS + kn,            &As[s][(sr +   0) * 64]);
    load_lds16(agS + 128 * Ks + kn, &As[s][(sr + 128) * 64]);
  };
  auto SAq1 = [&](int s, size_t kn) {            // frag rows 4-7
    load_lds16(agS +  64 * Ks + kn, &As[s][(sr +  64) * 64]);
    load_lds16(agS + 192 * Ks + kn, &As[s][(sr + 192) * 64]);
  };
  auto SB01 = [&](int s, size_t kn) {
    load_lds16(bgS + kn,            &Bs[s][(sr +   0) * 64]);
    load_lds16(bgS +  64 * Ks + kn, &Bs[s][(sr +  64) * 64]);
  };
  auto SB2 = [&](int s, size_t kn) {
    load_lds16(bgS + 128 * Ks + kn, &Bs[s][(sr + 128) * 64]);
    if constexpr (NFRAG == 4)
      load_lds16(bgS + 192 * Ks + kn, &Bs[s][(sr + 192) * 64]);
  };

  // ---- prologue: full tile0, tile1 minus Aq1 (staged at iter0 ph1) ----
  SAq0(0, 0); SAq1(0, 0); SB01(0, 0); SB2(0, 0);
  SAq0(1, 64); SB01(1, 64); SB2(1, 64);
  VMCNT(0);
  BARRIER();

#define LDA(s, i, ks) (*(const short8*)((const char*)&As[s][0] + rowA + (i) * 2048 + ((ks) ? cb1 : cb0)))
#define LDB(s, f, ks) (*(const short8*)((const char*)&Bs[s][0] + rowB + (f) * 2048 + ((ks) ? cb1 : cb0)))

  const int NI = K >> 7;                         // iters of 2 K-tiles
  for (int it = 0; it < NI; ++it) {
    const size_t kt0 = (size_t)it << 7;          // ushort col offset of t0
    const size_t k1 = kt0 + 64, k2 = kt0 + 128, k3 = kt0 + 192;
    const bool st2 = (it + 1 < NI);              // tiles t2 (=k2) valid
    const bool st3 = st2;                        // t3 valid iff t2 (NT even)

    short8 aR[4], bR[NFRAG][2], bS[NFRAG][2];

#define MFMA_PH(base, barr, ks)                                              \
    __builtin_amdgcn_s_setprio(1);                                          \
    _Pragma("unroll")                                                       \
    for (int i = 0; i < 4; ++i)                                             \
      _Pragma("unroll")                                                     \
      for (int f = 0; f < NFRAG; ++f)                                       \
        acc[(base) + i][f] = __builtin_amdgcn_mfma_f32_16x16x32_bf16(       \
            aR[i], barr[f][ks], acc[(base) + i][f], 0, 0, 0);               \
    __builtin_amdgcn_s_setprio(0);

    // ---- ph1: (t0, lo, ks0); reads A + full B[t0]; stage Aq1[t1] ----
#pragma unroll
    for (int i = 0; i < 4; ++i) aR[i] = LDA(0, i, 0);
#pragma unroll
    for (int f = 0; f < NFRAG; ++f) { bR[f][0] = LDB(0, f, 0); bR[f][1] = LDB(0, f, 1); }
    SAq1(1, k1);
    VMCNT(4);                                    // covers <= prev ph7 (Aq0[t1], B[t1])
    BARRIER();
    LGKM0(); __builtin_amdgcn_sched_barrier(0);
    MFMA_PH(0, bR, 0)
    BARRIER();

    // ---- ph2: (t1, lo, ks0); reads A + full B[t1]; stage B01[t2] ----
#pragma unroll
    for (int i = 0; i < 4; ++i) aR[i] = LDA(1, i, 0);
#pragma unroll
    for (int f = 0; f < NFRAG; ++f) { bS[f][0] = LDB(1, f, 0); bS[f][1] = LDB(1, f, 1); }
    if (st2) SB01(0, k2);
    VMCNT(4);                                    // covers <= prev ph8 (Aq1[t0])
    BARRIER();
    LGKM0(); __builtin_amdgcn_sched_barrier(0);
    MFMA_PH(0, bS, 0)
    BARRIER();

    // ---- ph3: (t0, hi, ks0); stage B2[t2] ----
#pragma unroll
    for (int i = 0; i < 4; ++i) aR[i] = LDA(0, 4 + i, 0);
    if (st2) SB2(0, k2);
    if constexpr (NFRAG == 4) { VMCNT(4); } else { VMCNT(3); }  // covers <= ph1 (Aq1[t1])
    BARRIER();
    LGKM0(); __builtin_amdgcn_sched_barrier(0);
    MFMA_PH(4, bR, 0)
    BARRIER();

    // ---- ph4: (t1, hi, ks0); stage B01[t3] ----
#pragma unroll
    for (int i = 0; i < 4; ++i) aR[i] = LDA(1, 4 + i, 0);
    if (st3) SB01(1, k3);
    BARRIER();
    LGKM0(); __builtin_amdgcn_sched_barrier(0);
    MFMA_PH(4, bS, 0)
    BARRIER();

    // ---- ph5: (t0, lo, ks1); stage B2[t3] ----
#pragma unroll
    for (int i = 0; i < 4; ++i) aR[i] = LDA(0, i, 1);
    if (st3) SB2(1, k3);
    BARRIER();
    LGKM0(); __builtin_amdgcn_sched_barrier(0);
    MFMA_PH(0, bR, 1)
    BARRIER();

    // ---- ph6: (t1, lo, ks1); stage Aq0[t2] ----
#pragma unroll
    for (int i = 0; i < 4; ++i) aR[i] = LDA(1, i, 1);
    if (st2) SAq0(0, k2);
    BARRIER();
    LGKM0(); __builtin_amdgcn_sched_barrier(0);
    MFMA_PH(0, bS, 1)
    BARRIER();

    // ---- ph7: (t0, hi, ks1); stage Aq0[t3] ----
#pragma unroll
    for (int i = 0; i < 4; ++i) aR[i] = LDA(0, 4 + i, 1);
    if (st3) SAq0(1, k3);
    BARRIER();
    LGKM0(); __builtin_amdgcn_sched_barrier(0);
    MFMA_PH(4, bR, 1)
    BARRIER();

    // ---- ph8: (t1, hi, ks1); stage Aq1[t2] ----
#pragma unroll
    for (int i = 0; i < 4; ++i) aR[i] = LDA(1, 4 + i, 1);
    if (st2) SAq1(0, k2);
    VMCNT(4);                                    // covers <= ph6 (Aq0[t2] + B[t2])
    BARRIER();
    LGKM0(); __builtin_amdgcn_sched_barrier(0);
    MFMA_PH(4, bS, 1)
    BARRIER();

#undef MFMA_PH
  }
#undef LDA
#undef LDB

  // ---- epilogue ----
  const int r4 = (lane >> 4) << 2;
#pragma unroll
  for (int i = 0; i < 8; ++i) {
#pragma unroll
    for (int rr = 0; rr < 4; ++rr) {
      const size_t row = (size_t)(m0 + wm * 128 + i * 16 + r4 + rr);
#pragma unroll
      for (int f = 0; f < NFRAG; ++f) {
        const size_t col = (size_t)(n0 + wn * 16 * NFRAG + f * 16 + fr);
        if constexpr (OBF16)
          ((ushort_t*)Cp)[row * N + col] = f2bf(acc[i][f][rr]);
        else
          ((float*)Cp)[row * N + col] = acc[i][f][rr];
      }
    }
  }
}

// ---------------------------------------------------------------------------
// Flash attention, causal + ALiBi-sqrt (unchanged from R4/R5).
// ---------------------------------------------------------------------------
__global__ __launch_bounds__(256, 2)
void attn_fwd(const ushort_t* __restrict__ qkv,
              const ushort_t* __restrict__ vt,
              ushort_t* __restrict__ attn)
{
  __shared__ __align__(16) ushort_t Plds[4][32 * 40];

  const int bid = blockIdx.x;          // 512 blocks
  const int x   = bid & 7;
  const int p   = bid >> 3;
  const int j   = p & 15;
  const int g   = ((p >> 4) << 3) + x;
  const int b   = g >> 3;
  const int hkv = g & 7;

  const int tid  = threadIdx.x;
  const int wid  = tid >> 6, lane = tid & 63;
  const int h    = hkv * 4 + wid;
  const int fr   = lane & 15;
  const int kk8  = (lane >> 4) << 3;
  const int q4   = (lane >> 4) << 2;
  const float slope = exp2f(-0.25f * (float)(h + 1));
  const float scale = 0.08838834764831845f;

  const ushort_t* qp  = qkv + (size_t)b * Sc * QKVO + (size_t)h * Dc;
  const ushort_t* kp  = qkv + (size_t)b * Sc * QKVO + NHc * Dc + (size_t)hkv * Dc;
  const ushort_t* vtp = vt + (size_t)(b * NKVc + hkv) * Dc * Sc;
  ushort_t* myP = &Plds[wid][0];

  const floatx4 fz = {0.f, 0.f, 0.f, 0.f};

  auto process = [&](const int qb) {
    short8 qf[2][4];
#pragma unroll
    for (int t = 0; t < 2; ++t) {
      const int qrow = qb * 32 + t * 16 + fr;
#pragma unroll
      for (int s = 0; s < 4; ++s)
        qf[t][s] = *(const short8*)(qp + (size_t)qrow * QKVO + s * 32 + kk8);
    }

    floatx4 o[2][8];
#pragma unroll
    for (int t = 0; t < 2; ++t)
#pragma unroll
      for (int jj = 0; jj < 8; ++jj) o[t][jj] = fz;
    float mrow[2][4], lrow[2][4];
#pragma unroll
    for (int t = 0; t < 2; ++t)
#pragma unroll
      for (int rr = 0; rr < 4; ++rr) { mrow[t][rr] = -1e30f; lrow[t][rr] = 0.f; }

    for (int kb = 0; kb <= qb; ++kb) {
      floatx4 s_[2][2];
      s_[0][0] = fz; s_[0][1] = fz; s_[1][0] = fz; s_[1][1] = fz;
#pragma unroll
      for (int half = 0; half < 2; ++half) {
        const int kcol = kb * 32 + half * 16 + fr;
#pragma unroll
        for (int s = 0; s < 4; ++s) {
          const short8 kf = *(const short8*)(kp + (size_t)kcol * QKVO + s * 32 + kk8);
          s_[0][half] = __builtin_amdgcn_mfma_f32_16x16x32_bf16(qf[0][s], kf, s_[0][half], 0, 0, 0);
          s_[1][half] = __builtin_amdgcn_mfma_f32_16x16x32_bf16(qf[1][s], kf, s_[1][half], 0, 0, 0);
        }
      }

      short8 vf[8];
#pragma unroll
      for (int jj = 0; jj < 8; ++jj)
        vf[jj] = *(const short8*)(vtp + (size_t)(jj * 16 + fr) * Sc + kb * 32 + kk8);

#pragma unroll
      for (int t = 0; t < 2; ++t)
#pragma unroll
        for (int rr = 0; rr < 4; ++rr) {
          const int qg  = qb * 32 + t * 16 + q4 + rr;
          const int dk0 = qg - (kb * 32 + fr);
          const int dk1 = dk0 - 16;
          s_[t][0][rr] = (dk0 >= 0)
              ? s_[t][0][rr] * scale - slope * sqrtf((float)dk0) : -1e30f;
          s_[t][1][rr] = (dk1 >= 0)
              ? s_[t][1][rr] * scale - slope * sqrtf((float)dk1) : -1e30f;
        }

      float pmv[2][4];
#pragma unroll
      for (int t = 0; t < 2; ++t)
#pragma unroll
        for (int rr = 0; rr < 4; ++rr) {
          float pm = fmaxf(s_[t][0][rr], s_[t][1][rr]);
#pragma unroll
          for (int m = 1; m < 16; m <<= 1) pm = fmaxf(pm, __shfl_xor(pm, m));
          pmv[t][rr] = pm;
        }

      int need = 0;
#pragma unroll
      for (int t = 0; t < 2; ++t)
#pragma unroll
        for (int rr = 0; rr < 4; ++rr)
          need |= (pmv[t][rr] > mrow[t][rr] + 8.f) ? 1 : 0;
      if (__any(need)) {
#pragma unroll
        for (int t = 0; t < 2; ++t)
#pragma unroll
          for (int rr = 0; rr < 4; ++rr) {
            const float mnew = fmaxf(mrow[t][rr], pmv[t][rr]);
            const float corr = __expf(mrow[t][rr] - mnew);
            lrow[t][rr] *= corr;
            mrow[t][rr] = mnew;
#pragma unroll
            for (int jj = 0; jj < 8; ++jj) o[t][jj][rr] *= corr;
          }
      }

#pragma unroll
      for (int t = 0; t < 2; ++t)
#pragma unroll
        for (int rr = 0; rr < 4; ++rr) {
          const float p0 = __expf(s_[t][0][rr] - mrow[t][rr]);
          const float p1 = __expf(s_[t][1][rr] - mrow[t][rr]);
          lrow[t][rr] += p0 + p1;
          myP[(t * 16 + q4 + rr) * 40 + fr]      = f2bf(p0);
          myP[(t * 16 + q4 + rr) * 40 + 16 + fr] = f2bf(p1);
        }
      short8 pa[2];
      pa[0] = *(const short8*)&myP[fr * 40 + kk8];
      pa[1] = *(const short8*)&myP[(16 + fr) * 40 + kk8];

#pragma unroll
      for (int jj = 0; jj < 8; ++jj) {
        o[0][jj] = __builtin_amdgcn_mfma_f32_16x16x32_bf16(pa[0], vf[jj], o[0][jj], 0, 0, 0);
        o[1][jj] = __builtin_amdgcn_mfma_f32_16x16x32_bf16(pa[1], vf[jj], o[1][jj], 0, 0, 0);
      }
    }

#pragma unroll
    for (int t = 0; t < 2; ++t)
#pragma unroll
      for (int rr = 0; rr < 4; ++rr) {
        float rs = lrow[t][rr];
#pragma unroll
        for (int m = 1; m < 16; m <<= 1) rs += __shfl_xor(rs, m);
        const float inv = 1.f / rs;
        const size_t tok = (size_t)b * Sc + qb * 32 + t * 16 + q4 + rr;
#pragma unroll
        for (int jj = 0; jj < 8; ++jj)
          attn[tok * (size_t)(NHc * Dc) + h * Dc + jj * 16 + fr] = f2bf(o[t][jj][rr] * inv);
      }
  };

  process(31 - j);
  process(j);
}

// ---------------------------------------------------------------------------
extern "C" void kernel_launch(void* const* d_in, const int* in_sizes, int n_in,
                              void* d_out, int out_size, void* d_ws, size_t ws_size,
                              hipStream_t stream)
{
  const float* hidden = (const float*)d_in[0];
  const float* w_qkv  = (const float*)d_in[1];
  const float* w_o    = (const float*)d_in[2];
  float* out = (float*)d_out;

  // workspace layout (bf16 elems): 134.2 MB total
  ushort_t* wqT   = (ushort_t*)d_ws;                   // [6144][4096]  50.3MB
  ushort_t* hidb  = wqT + (size_t)QKVO * Hc;           // [4096][4096]  33.6MB
  ushort_t* qkvb  = hidb + (size_t)Mc * Hc;            // [4096][6144]  50.3MB
  ushort_t* attnb = hidb;                              // reuse after GEMM1
  ushort_t* woT   = wqT;                               // reuse after GEMM1
  ushort_t* vtb   = wqT + (size_t)Mc * Hc;             // reuse: wqT+33.6MB, 8.4MB

  // 1) hidden -> bf16
  cvt_bf16<<<dim3((Mc * Hc / 8) / 256), dim3(256), 0, stream>>>(
      hidden, hidb, Mc * Hc / 8);
  // 2) w_qkv^T -> bf16  [6144][4096]
  transpose_cvt<<<dim3((Hc / 64) * (QKVO / 64)), dim3(256), 0, stream>>>(
      w_qkv, wqT, Hc, QKVO);
  // 3) qkv = hidden @ w_qkv   (256x192 tile -> 512 blocks = 2.0 rounds)
  gemm_nt8d<3, true><<<dim3((Mc / 256) * (QKVO / 192)), dim3(512), 0, stream>>>(
      hidb, wqT, qkvb, Mc, QKVO, Hc);
  // 4) V -> VT  [b][hkv][d][s]
  v_transpose<<<dim3(1024), dim3(256), 0, stream>>>(qkvb, vtb);
  // 5) attention
  attn_fwd<<<dim3(512), dim3(256), 0, stream>>>(qkvb, vtb, attnb);
  // 6) w_o^T -> bf16  [4096][4096]
  transpose_cvt<<<dim3((Hc / 64) * (Hc / 64)), dim3(256), 0, stream>>>(
      w_o, woT, Hc, Hc);
  // 7) out = attn @ w_o       (256x256 tile -> 256 blocks = 1.0 round)
  gemm_nt8d<4, false><<<dim3((Mc / 256) * (Hc / 256)), dim3(512), 0, stream>>>(
      attnb, woT, out, Mc, Hc, Hc);
}

// Round 12
// 561.188 us; speedup vs baseline: 1.1045x; 1.1045x over previous
//
#include <hip/hip_runtime.h>
#include <stdint.h>

typedef __attribute__((ext_vector_type(4))) float floatx4;
typedef __attribute__((ext_vector_type(8))) short short8;
typedef unsigned short ushort_t;

#define DEVI __device__ __forceinline__

// Problem constants
constexpr int Bc   = 4;
constexpr int Sc   = 1024;
constexpr int Hc   = 4096;
constexpr int NHc  = 32;
constexpr int NKVc = 8;
constexpr int Dc   = 128;
constexpr int QKVO = 6144;           // NH*D + 2*NKV*D
constexpr int Mc   = Bc * Sc;        // 4096 tokens

DEVI ushort_t f2bf(float f) {
  union { float f; unsigned u; } x; x.f = f;
  unsigned u = x.u;
  u += 0x7fffu + ((u >> 16) & 1u);   // RNE
  return (ushort_t)(u >> 16);
}

DEVI short8 cvt8(floatx4 a, floatx4 b) {
  short8 r;
  r[0] = (short)f2bf(a[0]); r[1] = (short)f2bf(a[1]);
  r[2] = (short)f2bf(a[2]); r[3] = (short)f2bf(a[3]);
  r[4] = (short)f2bf(b[0]); r[5] = (short)f2bf(b[1]);
  r[6] = (short)f2bf(b[2]); r[7] = (short)f2bf(b[3]);
  return r;
}

DEVI void load_lds16(const ushort_t* g, ushort_t* l) {
  __builtin_amdgcn_global_load_lds(
      (const __attribute__((address_space(1))) void*)g,
      (__attribute__((address_space(3))) void*)l, 16, 0, 0);
}

#define BARRIER()  asm volatile("s_barrier" ::: "memory")
#define LGKM0()    asm volatile("s_waitcnt lgkmcnt(0)" ::: "memory")
#define VMCNT(n)   asm volatile("s_waitcnt vmcnt(" #n ")" ::: "memory")

// ---------------------------------------------------------------------------
// f32 -> bf16 plain convert (8 elems/thread)
// ---------------------------------------------------------------------------
__global__ __launch_bounds__(256)
void cvt_bf16(const float* __restrict__ src, ushort_t* __restrict__ dst, int n8)
{
  const int i = blockIdx.x * 256 + threadIdx.x;
  if (i >= n8) return;
  const floatx4 f0 = *(const floatx4*)(src + (size_t)i * 8);
  const floatx4 f1 = *(const floatx4*)(src + (size_t)i * 8 + 4);
  *(short8*)(dst + (size_t)i * 8) = cvt8(f0, f1);
}

// ---------------------------------------------------------------------------
// transpose + convert: src[R][C] f32 -> dst[C][R] bf16.  64x64 tiles.
// ---------------------------------------------------------------------------
__global__ __launch_bounds__(256)
void transpose_cvt(const float* __restrict__ src, ushort_t* __restrict__ dst,
                   int R, int C)
{
  __shared__ float ts[64][67];
  const int cb = C >> 6;
  const int r0 = (blockIdx.x / cb) << 6;
  const int c0 = (blockIdx.x % cb) << 6;
  const int t  = threadIdx.x;

  const int lr = t >> 4, lc = (t & 15) << 2;
#pragma unroll
  for (int i = 0; i < 4; ++i) {
    const floatx4 v = *(const floatx4*)(src + (size_t)(r0 + lr + 16 * i) * C + c0 + lc);
#pragma unroll
    for (int j = 0; j < 4; ++j) ts[lr + 16 * i][lc + j] = v[j];
  }
  __syncthreads();

  const int c     = ((t >> 6) << 4) + ((t & 63) >> 2);
  const int chunk = t & 3;
  short8 t0, t1;
#pragma unroll
  for (int k = 0; k < 8; ++k) t0[k] = (short)f2bf(ts[chunk * 16 + k][c]);
#pragma unroll
  for (int k = 0; k < 8; ++k) t1[k] = (short)f2bf(ts[chunk * 16 + 8 + k][c]);
  ushort_t* dp = dst + (size_t)(c0 + c) * R + r0 + chunk * 16;
  *(short8*)dp       = t0;
  *(short8*)(dp + 8) = t1;
}

// ---------------------------------------------------------------------------
// V transpose (bf16 -> bf16): qkv[b][s][5120 + hkv*128 + d] -> vt[b][hkv][d][s]
// ---------------------------------------------------------------------------
__global__ __launch_bounds__(256)
void v_transpose(const ushort_t* __restrict__ qkv, ushort_t* __restrict__ vt)
{
  __shared__ ushort_t ts[64][72];
  const int bid = blockIdx.x;
  const int db  = bid & 1;
  const int sb  = (bid >> 1) & 15;
  const int hkv = (bid >> 5) & 7;
  const int b   = bid >> 8;
  const int t   = threadIdx.x;

  const ushort_t* src = qkv + (size_t)(b * Sc + sb * 64) * QKVO
                        + (NHc * Dc + NKVc * Dc) + hkv * Dc + db * 64;
  const int lr = t >> 3, lc = (t & 7) * 8;
  *(short8*)&ts[lr][lc]      = *(const short8*)(src + (size_t)lr * QKVO + lc);
  *(short8*)&ts[lr + 32][lc] = *(const short8*)(src + (size_t)(lr + 32) * QKVO + lc);
  __syncthreads();

  ushort_t* dst = vt + ((size_t)(b * NKVc + hkv) * Dc + db * 64) * Sc + sb * 64;
  const int dr  = t >> 2;
  const int sc0 = (t & 3) * 16;
  short8 o0, o1;
#pragma unroll
  for (int k = 0; k < 8; ++k) o0[k] = (short)ts[sc0 + k][dr];
#pragma unroll
  for (int k = 0; k < 8; ++k) o1[k] = (short)ts[sc0 + 8 + k][dr];
  *(short8*)(dst + (size_t)dr * Sc + sc0)     = o0;
  *(short8*)(dst + (size_t)dr * Sc + sc0 + 8) = o1;
}

// ---------------------------------------------------------------------------
// Deep-pipeline GEMM (R11): iter = 2 K-tiles, 8 phases, B fully to regs.
// Used for GEMM1 at NFRAG=3 (VGPR fits; measured 215us, MfmaUtil 42%).
// ---------------------------------------------------------------------------
template<int NFRAG, bool OBF16>
__global__ __launch_bounds__(512, 2)
void gemm_nt8d(const ushort_t* __restrict__ A, const ushort_t* __restrict__ BT,
               void* __restrict__ Cp, int M, int N, int K)
{
  constexpr int BN = 64 * NFRAG;
  __shared__ __align__(16) ushort_t As[2][256 * 64];
  __shared__ __align__(16) ushort_t Bs[2][BN * 64];

  const int nb  = N / BN;
  const int nwg = (M >> 8) * nb;
  int bid = blockIdx.x;
  bid = (bid & 7) * (nwg >> 3) + (bid >> 3);     // XCD swizzle (nwg%8==0)
  const int bm = bid / nb, bn = bid % nb;
  const int m0 = bm << 8, n0 = bn * BN;

  const int tid  = threadIdx.x;
  const int wid  = tid >> 6, lane = tid & 63;
  const int wm   = wid >> 2, wn = wid & 3;       // wave grid 2x4
  const int fr   = lane & 15;
  const int g16  = (lane >> 4) << 4;             // frag k byte base
  const int rsw  = (fr & 7) << 4;                // read-side XOR
  const int l8   = lane >> 3;
  const int scol = ((lane & 7) ^ l8) << 3;       // pre-swizzled src col (ushorts)

  const int sr   = (wid << 3);                   // wave staging row base
  const size_t Ks = (size_t)K;
  const ushort_t* agS = A  + (size_t)(m0 + sr + l8) * K + scol;
  const ushort_t* bgS = BT + (size_t)(n0 + sr + l8) * K + scol;

  const int rowA = (wm * 128 + fr) * 128;        // byte base for A frag reads
  const int rowB = (wn * 16 * NFRAG + fr) * 128;
  const int cb0  = g16 ^ rsw;
  const int cb1  = (64 + g16) ^ rsw;

  const floatx4 fz = {0.f, 0.f, 0.f, 0.f};
  floatx4 acc[8][NFRAG];
#pragma unroll
  for (int i = 0; i < 8; ++i)
#pragma unroll
    for (int f = 0; f < NFRAG; ++f) acc[i][f] = fz;

  auto SAq0 = [&](int s, size_t kn) {
    load_lds16(agS + kn,            &As[s][(sr +   0) * 64]);
    load_lds16(agS + 128 * Ks + kn, &As[s][(sr + 128) * 64]);
  };
  auto SAq1 = [&](int s, size_t kn) {
    load_lds16(agS +  64 * Ks + kn, &As[s][(sr +  64) * 64]);
    load_lds16(agS + 192 * Ks + kn, &As[s][(sr + 192) * 64]);
  };
  auto SB01 = [&](int s, size_t kn) {
    load_lds16(bgS + kn,            &Bs[s][(sr +   0) * 64]);
    load_lds16(bgS +  64 * Ks + kn, &Bs[s][(sr +  64) * 64]);
  };
  auto SB2 = [&](int s, size_t kn) {
    load_lds16(bgS + 128 * Ks + kn, &Bs[s][(sr + 128) * 64]);
    if constexpr (NFRAG == 4)
      load_lds16(bgS + 192 * Ks + kn, &Bs[s][(sr + 192) * 64]);
  };

  // ---- prologue: full tile0, tile1 minus Aq1 (staged at iter0 ph1) ----
  SAq0(0, 0); SAq1(0, 0); SB01(0, 0); SB2(0, 0);
  SAq0(1, 64); SB01(1, 64); SB2(1, 64);
  VMCNT(0);
  BARRIER();

#define LDA(s, i, ks) (*(const short8*)((const char*)&As[s][0] + rowA + (i) * 2048 + ((ks) ? cb1 : cb0)))
#define LDB(s, f, ks) (*(const short8*)((const char*)&Bs[s][0] + rowB + (f) * 2048 + ((ks) ? cb1 : cb0)))

  const int NI = K >> 7;                         // iters of 2 K-tiles
  for (int it = 0; it < NI; ++it) {
    const size_t kt0 = (size_t)it << 7;
    const size_t k1 = kt0 + 64, k2 = kt0 + 128, k3 = kt0 + 192;
    const bool st2 = (it + 1 < NI);
    const bool st3 = st2;

    short8 aR[4], bR[NFRAG][2], bS[NFRAG][2];

#define MFMA_PH(base, barr, ks)                                              \
    __builtin_amdgcn_s_setprio(1);                                          \
    _Pragma("unroll")                                                       \
    for (int i = 0; i < 4; ++i)                                             \
      _Pragma("unroll")                                                     \
      for (int f = 0; f < NFRAG; ++f)                                       \
        acc[(base) + i][f] = __builtin_amdgcn_mfma_f32_16x16x32_bf16(       \
            aR[i], barr[f][ks], acc[(base) + i][f], 0, 0, 0);               \
    __builtin_amdgcn_s_setprio(0);

    // ---- ph1: (t0, lo, ks0); reads A + full B[t0]; stage Aq1[t1] ----
#pragma unroll
    for (int i = 0; i < 4; ++i) aR[i] = LDA(0, i, 0);
#pragma unroll
    for (int f = 0; f < NFRAG; ++f) { bR[f][0] = LDB(0, f, 0); bR[f][1] = LDB(0, f, 1); }
    SAq1(1, k1);
    VMCNT(4);
    BARRIER();
    LGKM0(); __builtin_amdgcn_sched_barrier(0);
    MFMA_PH(0, bR, 0)
    BARRIER();

    // ---- ph2: (t1, lo, ks0); reads A + full B[t1]; stage B01[t2] ----
#pragma unroll
    for (int i = 0; i < 4; ++i) aR[i] = LDA(1, i, 0);
#pragma unroll
    for (int f = 0; f < NFRAG; ++f) { bS[f][0] = LDB(1, f, 0); bS[f][1] = LDB(1, f, 1); }
    if (st2) SB01(0, k2);
    VMCNT(4);
    BARRIER();
    LGKM0(); __builtin_amdgcn_sched_barrier(0);
    MFMA_PH(0, bS, 0)
    BARRIER();

    // ---- ph3: (t0, hi, ks0); stage B2[t2] ----
#pragma unroll
    for (int i = 0; i < 4; ++i) aR[i] = LDA(0, 4 + i, 0);
    if (st2) SB2(0, k2);
    if constexpr (NFRAG == 4) { VMCNT(4); } else { VMCNT(3); }
    BARRIER();
    LGKM0(); __builtin_amdgcn_sched_barrier(0);
    MFMA_PH(4, bR, 0)
    BARRIER();

    // ---- ph4: (t1, hi, ks0); stage B01[t3] ----
#pragma unroll
    for (int i = 0; i < 4; ++i) aR[i] = LDA(1, 4 + i, 0);
    if (st3) SB01(1, k3);
    BARRIER();
    LGKM0(); __builtin_amdgcn_sched_barrier(0);
    MFMA_PH(4, bS, 0)
    BARRIER();

    // ---- ph5: (t0, lo, ks1); stage B2[t3] ----
#pragma unroll
    for (int i = 0; i < 4; ++i) aR[i] = LDA(0, i, 1);
    if (st3) SB2(1, k3);
    BARRIER();
    LGKM0(); __builtin_amdgcn_sched_barrier(0);
    MFMA_PH(0, bR, 1)
    BARRIER();

    // ---- ph6: (t1, lo, ks1); stage Aq0[t2] ----
#pragma unroll
    for (int i = 0; i < 4; ++i) aR[i] = LDA(1, i, 1);
    if (st2) SAq0(0, k2);
    BARRIER();
    LGKM0(); __builtin_amdgcn_sched_barrier(0);
    MFMA_PH(0, bS, 1)
    BARRIER();

    // ---- ph7: (t0, hi, ks1); stage Aq0[t3] ----
#pragma unroll
    for (int i = 0; i < 4; ++i) aR[i] = LDA(0, 4 + i, 1);
    if (st3) SAq0(1, k3);
    BARRIER();
    LGKM0(); __builtin_amdgcn_sched_barrier(0);
    MFMA_PH(4, bR, 1)
    BARRIER();

    // ---- ph8: (t1, hi, ks1); stage Aq1[t2] ----
#pragma unroll
    for (int i = 0; i < 4; ++i) aR[i] = LDA(1, 4 + i, 1);
    if (st2) SAq1(0, k2);
    VMCNT(4);
    BARRIER();
    LGKM0(); __builtin_amdgcn_sched_barrier(0);
    MFMA_PH(4, bS, 1)
    BARRIER();

#undef MFMA_PH
  }
#undef LDA
#undef LDB

  // ---- epilogue ----
  const int r4 = (lane >> 4) << 2;
#pragma unroll
  for (int i = 0; i < 8; ++i) {
#pragma unroll
    for (int rr = 0; rr < 4; ++rr) {
      const size_t row = (size_t)(m0 + wm * 128 + i * 16 + r4 + rr);
#pragma unroll
      for (int f = 0; f < NFRAG; ++f) {
        const size_t col = (size_t)(n0 + wn * 16 * NFRAG + f * 16 + fr);
        if constexpr (OBF16)
          ((ushort_t*)Cp)[row * N + col] = f2bf(acc[i][f][rr]);
        else
          ((float*)Cp)[row * N + col] = acc[i][f][rr];
      }
    }
  }
}

// ---------------------------------------------------------------------------
// Shallow 8-phase GEMM (R9): low VGPR (104), used for GEMM2 at NFRAG=4
// (measured ~170-185us; deep pipeline at NFRAG=4 regressed to ~258 from
// register pressure).
// ---------------------------------------------------------------------------
template<int NFRAG, bool OBF16>
__global__ __launch_bounds__(512, 2)
void gemm_nt8(const ushort_t* __restrict__ A, const ushort_t* __restrict__ BT,
              void* __restrict__ Cp, int M, int N, int K)
{
  constexpr int BN = 64 * NFRAG;
  __shared__ __align__(16) ushort_t As[2][256 * 64];
  __shared__ __align__(16) ushort_t Bs[2][BN * 64];

  const int nb  = N / BN;
  const int nwg = (M >> 8) * nb;
  int bid = blockIdx.x;
  bid = (bid & 7) * (nwg >> 3) + (bid >> 3);     // XCD swizzle (nwg%8==0)
  const int bm = bid / nb, bn = bid % nb;
  const int m0 = bm << 8, n0 = bn * BN;

  const int tid  = threadIdx.x;
  const int wid  = tid >> 6, lane = tid & 63;
  const int wm   = wid >> 2, wn = wid & 3;
  const int fr   = lane & 15;
  const int g16  = (lane >> 4) << 4;
  const int rsw  = (fr & 7) << 4;
  const int l8   = lane >> 3;
  const int scol = ((lane & 7) ^ l8) << 3;

  const int sr   = (wid << 3);
  const size_t Ks = (size_t)K;
  const ushort_t* agS = A  + (size_t)(m0 + sr + l8) * K + scol;
  const ushort_t* bgS = BT + (size_t)(n0 + sr + l8) * K + scol;

  const int rowA = (wm * 128 + fr) * 128;
  const int rowB = (wn * 16 * NFRAG + fr) * 128;
  const int cb0  = g16 ^ rsw;
  const int cb1  = (64 + g16) ^ rsw;

  const floatx4 fz = {0.f, 0.f, 0.f, 0.f};
  floatx4 acc[8][NFRAG];
#pragma unroll
  for (int i = 0; i < 8; ++i)
#pragma unroll
    for (int f = 0; f < NFRAG; ++f) acc[i][f] = fz;

  auto STB = [&](int v, size_t kn) {
#pragma unroll
    for (int j = 0; j < NFRAG; ++j)
      load_lds16(bgS + (size_t)(64 * j) * Ks + kn, &Bs[v][(sr + 64 * j) * 64]);
  };
  auto STA = [&](int v, size_t kn) {
    load_lds16(agS + kn,            &As[v][(sr +   0) * 64]);
    load_lds16(agS + 128 * Ks + kn, &As[v][(sr + 128) * 64]);
    load_lds16(agS +  64 * Ks + kn, &As[v][(sr +  64) * 64]);
    load_lds16(agS + 192 * Ks + kn, &As[v][(sr + 192) * 64]);
  };

  STB(0, 0); STA(0, 0);
  VMCNT(2);
  BARRIER();

  const int NT = K >> 6;
  for (int kt = 0; kt < NT; ++kt) {
    const int u = kt & 1, v = u ^ 1;
    const char* Au = (const char*)&As[u][0];
    const char* Bu = (const char*)&Bs[u][0];
    const bool st  = (kt + 1 < NT);
    const size_t kn = (size_t)(kt + 1) << 6;

#define LDA(i, ks) (*(const short8*)(Au + rowA + (i) * 2048 + ((ks) ? cb1 : cb0)))
#define LDB(f, ks) (*(const short8*)(Bu + rowB + (f) * 2048 + ((ks) ? cb1 : cb0)))

    short8 aR[4], bR[NFRAG];

    // phase 0: Mlo x ks0 (reads; stage B)
#pragma unroll
    for (int i = 0; i < 4; ++i) aR[i] = LDA(i, 0);
#pragma unroll
    for (int f = 0; f < NFRAG; ++f) bR[f] = LDB(f, 0);
    if (st) {
      STB(v, kn);
      if constexpr (NFRAG == 4) { VMCNT(4); } else { VMCNT(3); }
    } else { VMCNT(0); }
    BARRIER();
    LGKM0(); __builtin_amdgcn_sched_barrier(0);
    __builtin_amdgcn_s_setprio(1);
#pragma unroll
    for (int i = 0; i < 4; ++i)
#pragma unroll
      for (int f = 0; f < NFRAG; ++f)
        acc[i][f] = __builtin_amdgcn_mfma_f32_16x16x32_bf16(aR[i], bR[f], acc[i][f], 0, 0, 0);
    __builtin_amdgcn_s_setprio(0);
    BARRIER();

    // phase 1: Mhi x ks0 (reads; stage A)
#pragma unroll
    for (int i = 0; i < 4; ++i) aR[i] = LDA(4 + i, 0);
    if (st) STA(v, kn);
    BARRIER();
    LGKM0(); __builtin_amdgcn_sched_barrier(0);
    __builtin_amdgcn_s_setprio(1);
#pragma unroll
    for (int i = 0; i < 4; ++i)
#pragma unroll
      for (int f = 0; f < NFRAG; ++f)
        acc[4 + i][f] = __builtin_amdgcn_mfma_f32_16x16x32_bf16(aR[i], bR[f], acc[4 + i][f], 0, 0, 0);
    __builtin_amdgcn_s_setprio(0);
    BARRIER();

    // phase 2: Mhi x ks1
#pragma unroll
    for (int i = 0; i < 4; ++i) aR[i] = LDA(4 + i, 1);
#pragma unroll
    for (int f = 0; f < NFRAG; ++f) bR[f] = LDB(f, 1);
    BARRIER();
    LGKM0(); __builtin_amdgcn_sched_barrier(0);
    __builtin_amdgcn_s_setprio(1);
#pragma unroll
    for (int i = 0; i < 4; ++i)
#pragma unroll
      for (int f = 0; f < NFRAG; ++f)
        acc[4 + i][f] = __builtin_amdgcn_mfma_f32_16x16x32_bf16(aR[i], bR[f], acc[4 + i][f], 0, 0, 0);
    __builtin_amdgcn_s_setprio(0);
    BARRIER();

    // phase 3: Mlo x ks1
#pragma unroll
    for (int i = 0; i < 4; ++i) aR[i] = LDA(i, 1);
    if (st) { VMCNT(2); }
    BARRIER();
    LGKM0(); __builtin_amdgcn_sched_barrier(0);
    __builtin_amdgcn_s_setprio(1);
#pragma unroll
    for (int i = 0; i < 4; ++i)
#pragma unroll
      for (int f = 0; f < NFRAG; ++f)
        acc[i][f] = __builtin_amdgcn_mfma_f32_16x16x32_bf16(aR[i], bR[f], acc[i][f], 0, 0, 0);
    __builtin_amdgcn_s_setprio(0);
    BARRIER();

#undef LDA
#undef LDB
  }

  const int r4 = (lane >> 4) << 2;
#pragma unroll
  for (int i = 0; i < 8; ++i) {
#pragma unroll
    for (int rr = 0; rr < 4; ++rr) {
      const size_t row = (size_t)(m0 + wm * 128 + i * 16 + r4 + rr);
#pragma unroll
      for (int f = 0; f < NFRAG; ++f) {
        const size_t col = (size_t)(n0 + wn * 16 * NFRAG + f * 16 + fr);
        if constexpr (OBF16)
          ((ushort_t*)Cp)[row * N + col] = f2bf(acc[i][f][rr]);
        else
          ((float*)Cp)[row * N + col] = acc[i][f][rr];
      }
    }
  }
}

// ---------------------------------------------------------------------------
// Flash attention, causal + ALiBi-sqrt (unchanged from R4/R5).
// ---------------------------------------------------------------------------
__global__ __launch_bounds__(256, 2)
void attn_fwd(const ushort_t* __restrict__ qkv,
              const ushort_t* __restrict__ vt,
              ushort_t* __restrict__ attn)
{
  __shared__ __align__(16) ushort_t Plds[4][32 * 40];

  const int bid = blockIdx.x;          // 512 blocks
  const int x   = bid & 7;
  const int p   = bid >> 3;
  const int j   = p & 15;
  const int g   = ((p >> 4) << 3) + x;
  const int b   = g >> 3;
  const int hkv = g & 7;

  const int tid  = threadIdx.x;
  const int wid  = tid >> 6, lane = tid & 63;
  const int h    = hkv * 4 + wid;
  const int fr   = lane & 15;
  const int kk8  = (lane >> 4) << 3;
  const int q4   = (lane >> 4) << 2;
  const float slope = exp2f(-0.25f * (float)(h + 1));
  const float scale = 0.08838834764831845f;

  const ushort_t* qp  = qkv + (size_t)b * Sc * QKVO + (size_t)h * Dc;
  const ushort_t* kp  = qkv + (size_t)b * Sc * QKVO + NHc * Dc + (size_t)hkv * Dc;
  const ushort_t* vtp = vt + (size_t)(b * NKVc + hkv) * Dc * Sc;
  ushort_t* myP = &Plds[wid][0];

  const floatx4 fz = {0.f, 0.f, 0.f, 0.f};

  auto process = [&](const int qb) {
    short8 qf[2][4];
#pragma unroll
    for (int t = 0; t < 2; ++t) {
      const int qrow = qb * 32 + t * 16 + fr;
#pragma unroll
      for (int s = 0; s < 4; ++s)
        qf[t][s] = *(const short8*)(qp + (size_t)qrow * QKVO + s * 32 + kk8);
    }

    floatx4 o[2][8];
#pragma unroll
    for (int t = 0; t < 2; ++t)
#pragma unroll
      for (int jj = 0; jj < 8; ++jj) o[t][jj] = fz;
    float mrow[2][4], lrow[2][4];
#pragma unroll
    for (int t = 0; t < 2; ++t)
#pragma unroll
      for (int rr = 0; rr < 4; ++rr) { mrow[t][rr] = -1e30f; lrow[t][rr] = 0.f; }

    for (int kb = 0; kb <= qb; ++kb) {
      floatx4 s_[2][2];
      s_[0][0] = fz; s_[0][1] = fz; s_[1][0] = fz; s_[1][1] = fz;
#pragma unroll
      for (int half = 0; half < 2; ++half) {
        const int kcol = kb * 32 + half * 16 + fr;
#pragma unroll
        for (int s = 0; s < 4; ++s) {
          const short8 kf = *(const short8*)(kp + (size_t)kcol * QKVO + s * 32 + kk8);
          s_[0][half] = __builtin_amdgcn_mfma_f32_16x16x32_bf16(qf[0][s], kf, s_[0][half], 0, 0, 0);
          s_[1][half] = __builtin_amdgcn_mfma_f32_16x16x32_bf16(qf[1][s], kf, s_[1][half], 0, 0, 0);
        }
      }

      short8 vf[8];
#pragma unroll
      for (int jj = 0; jj < 8; ++jj)
        vf[jj] = *(const short8*)(vtp + (size_t)(jj * 16 + fr) * Sc + kb * 32 + kk8);

#pragma unroll
      for (int t = 0; t < 2; ++t)
#pragma unroll
        for (int rr = 0; rr < 4; ++rr) {
          const int qg  = qb * 32 + t * 16 + q4 + rr;
          const int dk0 = qg - (kb * 32 + fr);
          const int dk1 = dk0 - 16;
          s_[t][0][rr] = (dk0 >= 0)
              ? s_[t][0][rr] * scale - slope * sqrtf((float)dk0) : -1e30f;
          s_[t][1][rr] = (dk1 >= 0)
              ? s_[t][1][rr] * scale - slope * sqrtf((float)dk1) : -1e30f;
        }

      float pmv[2][4];
#pragma unroll
      for (int t = 0; t < 2; ++t)
#pragma unroll
        for (int rr = 0; rr < 4; ++rr) {
          float pm = fmaxf(s_[t][0][rr], s_[t][1][rr]);
#pragma unroll
          for (int m = 1; m < 16; m <<= 1) pm = fmaxf(pm, __shfl_xor(pm, m));
          pmv[t][rr] = pm;
        }

      int need = 0;
#pragma unroll
      for (int t = 0; t < 2; ++t)
#pragma unroll
        for (int rr = 0; rr < 4; ++rr)
          need |= (pmv[t][rr] > mrow[t][rr] + 8.f) ? 1 : 0;
      if (__any(need)) {
#pragma unroll
        for (int t = 0; t < 2; ++t)
#pragma unroll
          for (int rr = 0; rr < 4; ++rr) {
            const float mnew = fmaxf(mrow[t][rr], pmv[t][rr]);
            const float corr = __expf(mrow[t][rr] - mnew);
            lrow[t][rr] *= corr;
            mrow[t][rr] = mnew;
#pragma unroll
            for (int jj = 0; jj < 8; ++jj) o[t][jj][rr] *= corr;
          }
      }

#pragma unroll
      for (int t = 0; t < 2; ++t)
#pragma unroll
        for (int rr = 0; rr < 4; ++rr) {
          const float p0 = __expf(s_[t][0][rr] - mrow[t][rr]);
          const float p1 = __expf(s_[t][1][rr] - mrow[t][rr]);
          lrow[t][rr] += p0 + p1;
          myP[(t * 16 + q4 + rr) * 40 + fr]      = f2bf(p0);
          myP[(t * 16 + q4 + rr) * 40 + 16 + fr] = f2bf(p1);
        }
      short8 pa[2];
      pa[0] = *(const short8*)&myP[fr * 40 + kk8];
      pa[1] = *(const short8*)&myP[(16 + fr) * 40 + kk8];

#pragma unroll
      for (int jj = 0; jj < 8; ++jj) {
        o[0][jj] = __builtin_amdgcn_mfma_f32_16x16x32_bf16(pa[0], vf[jj], o[0][jj], 0, 0, 0);
        o[1][jj] = __builtin_amdgcn_mfma_f32_16x16x32_bf16(pa[1], vf[jj], o[1][jj], 0, 0, 0);
      }
    }

#pragma unroll
    for (int t = 0; t < 2; ++t)
#pragma unroll
      for (int rr = 0; rr < 4; ++rr) {
        float rs = lrow[t][rr];
#pragma unroll
        for (int m = 1; m < 16; m <<= 1) rs += __shfl_xor(rs, m);
        const float inv = 1.f / rs;
        const size_t tok = (size_t)b * Sc + qb * 32 + t * 16 + q4 + rr;
#pragma unroll
        for (int jj = 0; jj < 8; ++jj)
          attn[tok * (size_t)(NHc * Dc) + h * Dc + jj * 16 + fr] = f2bf(o[t][jj][rr] * inv);
      }
  };

  process(31 - j);
  process(j);
}

// ---------------------------------------------------------------------------
extern "C" void kernel_launch(void* const* d_in, const int* in_sizes, int n_in,
                              void* d_out, int out_size, void* d_ws, size_t ws_size,
                              hipStream_t stream)
{
  const float* hidden = (const float*)d_in[0];
  const float* w_qkv  = (const float*)d_in[1];
  const float* w_o    = (const float*)d_in[2];
  float* out = (float*)d_out;

  // workspace layout (bf16 elems): 134.2 MB total
  ushort_t* wqT   = (ushort_t*)d_ws;                   // [6144][4096]  50.3MB
  ushort_t* hidb  = wqT + (size_t)QKVO * Hc;           // [4096][4096]  33.6MB
  ushort_t* qkvb  = hidb + (size_t)Mc * Hc;            // [4096][6144]  50.3MB
  ushort_t* attnb = hidb;                              // reuse after GEMM1
  ushort_t* woT   = wqT;                               // reuse after GEMM1
  ushort_t* vtb   = wqT + (size_t)Mc * Hc;             // reuse: wqT+33.6MB, 8.4MB

  // 1) hidden -> bf16
  cvt_bf16<<<dim3((Mc * Hc / 8) / 256), dim3(256), 0, stream>>>(
      hidden, hidb, Mc * Hc / 8);
  // 2) w_qkv^T -> bf16  [6144][4096]
  transpose_cvt<<<dim3((Hc / 64) * (QKVO / 64)), dim3(256), 0, stream>>>(
      w_qkv, wqT, Hc, QKVO);
  // 3) qkv = hidden @ w_qkv   (deep pipeline, 256x192 -> 512 blocks = 2 rounds)
  gemm_nt8d<3, true><<<dim3((Mc / 256) * (QKVO / 192)), dim3(512), 0, stream>>>(
      hidb, wqT, qkvb, Mc, QKVO, Hc);
  // 4) V -> VT  [b][hkv][d][s]
  v_transpose<<<dim3(1024), dim3(256), 0, stream>>>(qkvb, vtb);
  // 5) attention
  attn_fwd<<<dim3(512), dim3(256), 0, stream>>>(qkvb, vtb, attnb);
  // 6) w_o^T -> bf16  [4096][4096]
  transpose_cvt<<<dim3((Hc / 64) * (Hc / 64)), dim3(256), 0, stream>>>(
      w_o, woT, Hc, Hc);
  // 7) out = attn @ w_o       (shallow pipeline, 256x256 -> 256 blocks = 1 round)
  gemm_nt8<4, false><<<dim3((Mc / 256) * (Hc / 256)), dim3(512), 0, stream>>>(
      attnb, woT, out, Mc, Hc, Hc);
}

// Round 13
// 559.729 us; speedup vs baseline: 1.1074x; 1.0026x over previous
//
#include <hip/hip_runtime.h>
#include <stdint.h>

typedef __attribute__((ext_vector_type(4))) float floatx4;
typedef __attribute__((ext_vector_type(8))) short short8;
typedef unsigned short ushort_t;

#define DEVI __device__ __forceinline__

// Problem constants
constexpr int Bc   = 4;
constexpr int Sc   = 1024;
constexpr int Hc   = 4096;
constexpr int NHc  = 32;
constexpr int NKVc = 8;
constexpr int Dc   = 128;
constexpr int QKVO = 6144;           // NH*D + 2*NKV*D
constexpr int Mc   = Bc * Sc;        // 4096 tokens

DEVI ushort_t f2bf(float f) {
  union { float f; unsigned u; } x; x.f = f;
  unsigned u = x.u;
  u += 0x7fffu + ((u >> 16) & 1u);   // RNE
  return (ushort_t)(u >> 16);
}

DEVI short8 cvt8(floatx4 a, floatx4 b) {
  short8 r;
  r[0] = (short)f2bf(a[0]); r[1] = (short)f2bf(a[1]);
  r[2] = (short)f2bf(a[2]); r[3] = (short)f2bf(a[3]);
  r[4] = (short)f2bf(b[0]); r[5] = (short)f2bf(b[1]);
  r[6] = (short)f2bf(b[2]); r[7] = (short)f2bf(b[3]);
  return r;
}

DEVI void load_lds16(const ushort_t* g, ushort_t* l) {
  __builtin_amdgcn_global_load_lds(
      (const __attribute__((address_space(1))) void*)g,
      (__attribute__((address_space(3))) void*)l, 16, 0, 0);
}

#define BARRIER()  asm volatile("s_barrier" ::: "memory")
#define LGKM0()    asm volatile("s_waitcnt lgkmcnt(0)" ::: "memory")
#define VMCNT(n)   asm volatile("s_waitcnt vmcnt(" #n ")" ::: "memory")

// ---------------------------------------------------------------------------
// f32 -> bf16 plain convert (8 elems/thread)
// ---------------------------------------------------------------------------
__global__ __launch_bounds__(256)
void cvt_bf16(const float* __restrict__ src, ushort_t* __restrict__ dst, int n8)
{
  const int i = blockIdx.x * 256 + threadIdx.x;
  if (i >= n8) return;
  const floatx4 f0 = *(const floatx4*)(src + (size_t)i * 8);
  const floatx4 f1 = *(const floatx4*)(src + (size_t)i * 8 + 4);
  *(short8*)(dst + (size_t)i * 8) = cvt8(f0, f1);
}

// ---------------------------------------------------------------------------
// transpose + convert: src[R][C] f32 -> dst[C][R] bf16.  64x64 tiles.
// ---------------------------------------------------------------------------
__global__ __launch_bounds__(256)
void transpose_cvt(const float* __restrict__ src, ushort_t* __restrict__ dst,
                   int R, int C)
{
  __shared__ float ts[64][67];
  const int cb = C >> 6;
  const int r0 = (blockIdx.x / cb) << 6;
  const int c0 = (blockIdx.x % cb) << 6;
  const int t  = threadIdx.x;

  const int lr = t >> 4, lc = (t & 15) << 2;
#pragma unroll
  for (int i = 0; i < 4; ++i) {
    const floatx4 v = *(const floatx4*)(src + (size_t)(r0 + lr + 16 * i) * C + c0 + lc);
#pragma unroll
    for (int j = 0; j < 4; ++j) ts[lr + 16 * i][lc + j] = v[j];
  }
  __syncthreads();

  const int c     = ((t >> 6) << 4) + ((t & 63) >> 2);
  const int chunk = t & 3;
  short8 t0, t1;
#pragma unroll
  for (int k = 0; k < 8; ++k) t0[k] = (short)f2bf(ts[chunk * 16 + k][c]);
#pragma unroll
  for (int k = 0; k < 8; ++k) t1[k] = (short)f2bf(ts[chunk * 16 + 8 + k][c]);
  ushort_t* dp = dst + (size_t)(c0 + c) * R + r0 + chunk * 16;
  *(short8*)dp       = t0;
  *(short8*)(dp + 8) = t1;
}

// ---------------------------------------------------------------------------
// V transpose (bf16 -> bf16): qkv[b][s][5120 + hkv*128 + d] -> vt[b][hkv][d][s]
// ---------------------------------------------------------------------------
__global__ __launch_bounds__(256)
void v_transpose(const ushort_t* __restrict__ qkv, ushort_t* __restrict__ vt)
{
  __shared__ ushort_t ts[64][72];
  const int bid = blockIdx.x;
  const int db  = bid & 1;
  const int sb  = (bid >> 1) & 15;
  const int hkv = (bid >> 5) & 7;
  const int b   = bid >> 8;
  const int t   = threadIdx.x;

  const ushort_t* src = qkv + (size_t)(b * Sc + sb * 64) * QKVO
                        + (NHc * Dc + NKVc * Dc) + hkv * Dc + db * 64;
  const int lr = t >> 3, lc = (t & 7) * 8;
  *(short8*)&ts[lr][lc]      = *(const short8*)(src + (size_t)lr * QKVO + lc);
  *(short8*)&ts[lr + 32][lc] = *(const short8*)(src + (size_t)(lr + 32) * QKVO + lc);
  __syncthreads();

  ushort_t* dst = vt + ((size_t)(b * NKVc + hkv) * Dc + db * 64) * Sc + sb * 64;
  const int dr  = t >> 2;
  const int sc0 = (t & 3) * 16;
  short8 o0, o1;
#pragma unroll
  for (int k = 0; k < 8; ++k) o0[k] = (short)ts[sc0 + k][dr];
#pragma unroll
  for (int k = 0; k < 8; ++k) o1[k] = (short)ts[sc0 + 8 + k][dr];
  *(short8*)(dst + (size_t)dr * Sc + sc0)     = o0;
  *(short8*)(dst + (size_t)dr * Sc + sc0 + 8) = o1;
}

// ---------------------------------------------------------------------------
// Deep-pipeline GEMM, tile-INTERLEAVED (R11).  GEMM1 @ NFRAG=3 (measured
// 215us, MfmaUtil 42%).
// ---------------------------------------------------------------------------
template<int NFRAG, bool OBF16>
__global__ __launch_bounds__(512, 2)
void gemm_nt8d(const ushort_t* __restrict__ A, const ushort_t* __restrict__ BT,
               void* __restrict__ Cp, int M, int N, int K)
{
  constexpr int BN = 64 * NFRAG;
  __shared__ __align__(16) ushort_t As[2][256 * 64];
  __shared__ __align__(16) ushort_t Bs[2][BN * 64];

  const int nb  = N / BN;
  const int nwg = (M >> 8) * nb;
  int bid = blockIdx.x;
  bid = (bid & 7) * (nwg >> 3) + (bid >> 3);
  const int bm = bid / nb, bn = bid % nb;
  const int m0 = bm << 8, n0 = bn * BN;

  const int tid  = threadIdx.x;
  const int wid  = tid >> 6, lane = tid & 63;
  const int wm   = wid >> 2, wn = wid & 3;
  const int fr   = lane & 15;
  const int g16  = (lane >> 4) << 4;
  const int rsw  = (fr & 7) << 4;
  const int l8   = lane >> 3;
  const int scol = ((lane & 7) ^ l8) << 3;

  const int sr   = (wid << 3);
  const size_t Ks = (size_t)K;
  const ushort_t* agS = A  + (size_t)(m0 + sr + l8) * K + scol;
  const ushort_t* bgS = BT + (size_t)(n0 + sr + l8) * K + scol;

  const int rowA = (wm * 128 + fr) * 128;
  const int rowB = (wn * 16 * NFRAG + fr) * 128;
  const int cb0  = g16 ^ rsw;
  const int cb1  = (64 + g16) ^ rsw;

  const floatx4 fz = {0.f, 0.f, 0.f, 0.f};
  floatx4 acc[8][NFRAG];
#pragma unroll
  for (int i = 0; i < 8; ++i)
#pragma unroll
    for (int f = 0; f < NFRAG; ++f) acc[i][f] = fz;

  auto SAq0 = [&](int s, size_t kn) {
    load_lds16(agS + kn,            &As[s][(sr +   0) * 64]);
    load_lds16(agS + 128 * Ks + kn, &As[s][(sr + 128) * 64]);
  };
  auto SAq1 = [&](int s, size_t kn) {
    load_lds16(agS +  64 * Ks + kn, &As[s][(sr +  64) * 64]);
    load_lds16(agS + 192 * Ks + kn, &As[s][(sr + 192) * 64]);
  };
  auto SB01 = [&](int s, size_t kn) {
    load_lds16(bgS + kn,            &Bs[s][(sr +   0) * 64]);
    load_lds16(bgS +  64 * Ks + kn, &Bs[s][(sr +  64) * 64]);
  };
  auto SB2 = [&](int s, size_t kn) {
    load_lds16(bgS + 128 * Ks + kn, &Bs[s][(sr + 128) * 64]);
    if constexpr (NFRAG == 4)
      load_lds16(bgS + 192 * Ks + kn, &Bs[s][(sr + 192) * 64]);
  };

  SAq0(0, 0); SAq1(0, 0); SB01(0, 0); SB2(0, 0);
  SAq0(1, 64); SB01(1, 64); SB2(1, 64);
  VMCNT(0);
  BARRIER();

#define LDA(s, i, ks) (*(const short8*)((const char*)&As[s][0] + rowA + (i) * 2048 + ((ks) ? cb1 : cb0)))
#define LDB(s, f, ks) (*(const short8*)((const char*)&Bs[s][0] + rowB + (f) * 2048 + ((ks) ? cb1 : cb0)))

  const int NI = K >> 7;
  for (int it = 0; it < NI; ++it) {
    const size_t kt0 = (size_t)it << 7;
    const size_t k1 = kt0 + 64, k2 = kt0 + 128, k3 = kt0 + 192;
    const bool st2 = (it + 1 < NI);
    const bool st3 = st2;

    short8 aR[4], bR[NFRAG][2], bS[NFRAG][2];

#define MFMA_PH(base, barr, ks)                                              \
    __builtin_amdgcn_s_setprio(1);                                          \
    _Pragma("unroll")                                                       \
    for (int i = 0; i < 4; ++i)                                             \
      _Pragma("unroll")                                                     \
      for (int f = 0; f < NFRAG; ++f)                                       \
        acc[(base) + i][f] = __builtin_amdgcn_mfma_f32_16x16x32_bf16(       \
            aR[i], barr[f][ks], acc[(base) + i][f], 0, 0, 0);               \
    __builtin_amdgcn_s_setprio(0);

#pragma unroll
    for (int i = 0; i < 4; ++i) aR[i] = LDA(0, i, 0);
#pragma unroll
    for (int f = 0; f < NFRAG; ++f) { bR[f][0] = LDB(0, f, 0); bR[f][1] = LDB(0, f, 1); }
    SAq1(1, k1);
    VMCNT(4);
    BARRIER();
    LGKM0(); __builtin_amdgcn_sched_barrier(0);
    MFMA_PH(0, bR, 0)
    BARRIER();

#pragma unroll
    for (int i = 0; i < 4; ++i) aR[i] = LDA(1, i, 0);
#pragma unroll
    for (int f = 0; f < NFRAG; ++f) { bS[f][0] = LDB(1, f, 0); bS[f][1] = LDB(1, f, 1); }
    if (st2) SB01(0, k2);
    VMCNT(4);
    BARRIER();
    LGKM0(); __builtin_amdgcn_sched_barrier(0);
    MFMA_PH(0, bS, 0)
    BARRIER();

#pragma unroll
    for (int i = 0; i < 4; ++i) aR[i] = LDA(0, 4 + i, 0);
    if (st2) SB2(0, k2);
    if constexpr (NFRAG == 4) { VMCNT(4); } else { VMCNT(3); }
    BARRIER();
    LGKM0(); __builtin_amdgcn_sched_barrier(0);
    MFMA_PH(4, bR, 0)
    BARRIER();

#pragma unroll
    for (int i = 0; i < 4; ++i) aR[i] = LDA(1, 4 + i, 0);
    if (st3) SB01(1, k3);
    BARRIER();
    LGKM0(); __builtin_amdgcn_sched_barrier(0);
    MFMA_PH(4, bS, 0)
    BARRIER();

#pragma unroll
    for (int i = 0; i < 4; ++i) aR[i] = LDA(0, i, 1);
    if (st3) SB2(1, k3);
    BARRIER();
    LGKM0(); __builtin_amdgcn_sched_barrier(0);
    MFMA_PH(0, bR, 1)
    BARRIER();

#pragma unroll
    for (int i = 0; i < 4; ++i) aR[i] = LDA(1, i, 1);
    if (st2) SAq0(0, k2);
    BARRIER();
    LGKM0(); __builtin_amdgcn_sched_barrier(0);
    MFMA_PH(0, bS, 1)
    BARRIER();

#pragma unroll
    for (int i = 0; i < 4; ++i) aR[i] = LDA(0, 4 + i, 1);
    if (st3) SAq0(1, k3);
    BARRIER();
    LGKM0(); __builtin_amdgcn_sched_barrier(0);
    MFMA_PH(4, bR, 1)
    BARRIER();

#pragma unroll
    for (int i = 0; i < 4; ++i) aR[i] = LDA(1, 4 + i, 1);
    if (st2) SAq1(0, k2);
    VMCNT(4);
    BARRIER();
    LGKM0(); __builtin_amdgcn_sched_barrier(0);
    MFMA_PH(4, bS, 1)
    BARRIER();

#undef MFMA_PH
  }
#undef LDA
#undef LDB

  const int r4 = (lane >> 4) << 2;
#pragma unroll
  for (int i = 0; i < 8; ++i) {
#pragma unroll
    for (int rr = 0; rr < 4; ++rr) {
      const size_t row = (size_t)(m0 + wm * 128 + i * 16 + r4 + rr);
#pragma unroll
      for (int f = 0; f < NFRAG; ++f) {
        const size_t col = (size_t)(n0 + wn * 16 * NFRAG + f * 16 + fr);
        if constexpr (OBF16)
          ((ushort_t*)Cp)[row * N + col] = f2bf(acc[i][f][rr]);
        else
          ((float*)Cp)[row * N + col] = acc[i][f][rr];
      }
    }
  }
}

// ---------------------------------------------------------------------------
// Deep-pipeline GEMM, tile-SEQUENTIAL (R12): iter = 2 K-tiles, t0's 4 phases
// then t1's 4 phases.  Only ONE B-block live in regs at a time (32 VGPR at
// NFRAG=4 vs 64 interleaved).  Stage map (2 loads/thread/phase):
//   ph1: Aq0[t1]  ph2: Aq1[t1]  ph3: B01[t2]  ph4: B2[t2]
//   ph5: Aq0[t2]  ph6: Aq1[t2]  ph7: B01[t3]  ph8: B2[t3]
// Forces (2/iter): end-ph4 VMCNT(4) -> A[t1] (d=2-3) + B[t1] (prev ph7-8,
// d=4-5); end-ph8 VMCNT(4) -> A[t2] (d=2-3) + B[t2] (d=4-5).  Every consume
// follows a barrier after the force in all waves.
// ---------------------------------------------------------------------------
template<int NFRAG, bool OBF16>
__global__ __launch_bounds__(512, 2)
void gemm_nt8s(const ushort_t* __restrict__ A, const ushort_t* __restrict__ BT,
               void* __restrict__ Cp, int M, int N, int K)
{
  constexpr int BN = 64 * NFRAG;
  __shared__ __align__(16) ushort_t As[2][256 * 64];
  __shared__ __align__(16) ushort_t Bs[2][BN * 64];

  const int nb  = N / BN;
  const int nwg = (M >> 8) * nb;
  int bid = blockIdx.x;
  bid = (bid & 7) * (nwg >> 3) + (bid >> 3);
  const int bm = bid / nb, bn = bid % nb;
  const int m0 = bm << 8, n0 = bn * BN;

  const int tid  = threadIdx.x;
  const int wid  = tid >> 6, lane = tid & 63;
  const int wm   = wid >> 2, wn = wid & 3;
  const int fr   = lane & 15;
  const int g16  = (lane >> 4) << 4;
  const int rsw  = (fr & 7) << 4;
  const int l8   = lane >> 3;
  const int scol = ((lane & 7) ^ l8) << 3;

  const int sr   = (wid << 3);
  const size_t Ks = (size_t)K;
  const ushort_t* agS = A  + (size_t)(m0 + sr + l8) * K + scol;
  const ushort_t* bgS = BT + (size_t)(n0 + sr + l8) * K + scol;

  const int rowA = (wm * 128 + fr) * 128;
  const int rowB = (wn * 16 * NFRAG + fr) * 128;
  const int cb0  = g16 ^ rsw;
  const int cb1  = (64 + g16) ^ rsw;

  const floatx4 fz = {0.f, 0.f, 0.f, 0.f};
  floatx4 acc[8][NFRAG];
#pragma unroll
  for (int i = 0; i < 8; ++i)
#pragma unroll
    for (int f = 0; f < NFRAG; ++f) acc[i][f] = fz;

  auto SAq0 = [&](int s, size_t kn) {
    load_lds16(agS + kn,            &As[s][(sr +   0) * 64]);
    load_lds16(agS + 128 * Ks + kn, &As[s][(sr + 128) * 64]);
  };
  auto SAq1 = [&](int s, size_t kn) {
    load_lds16(agS +  64 * Ks + kn, &As[s][(sr +  64) * 64]);
    load_lds16(agS + 192 * Ks + kn, &As[s][(sr + 192) * 64]);
  };
  auto SB01 = [&](int s, size_t kn) {
    load_lds16(bgS + kn,            &Bs[s][(sr +   0) * 64]);
    load_lds16(bgS +  64 * Ks + kn, &Bs[s][(sr +  64) * 64]);
  };
  auto SB2 = [&](int s, size_t kn) {
    load_lds16(bgS + 128 * Ks + kn, &Bs[s][(sr + 128) * 64]);
    if constexpr (NFRAG == 4)
      load_lds16(bgS + 192 * Ks + kn, &Bs[s][(sr + 192) * 64]);
  };

  // prologue: A[t0]+B[t0] full, B[t1]; force all but B[t1]
  SAq0(0, 0); SAq1(0, 0); SB01(0, 0); SB2(0, 0);
  SB01(1, 64); SB2(1, 64);
  VMCNT(4);
  BARRIER();

#define LDA(s, i, ks) (*(const short8*)((const char*)&As[s][0] + rowA + (i) * 2048 + ((ks) ? cb1 : cb0)))
#define LDB(s, f, ks) (*(const short8*)((const char*)&Bs[s][0] + rowB + (f) * 2048 + ((ks) ? cb1 : cb0)))

  const int NI = K >> 7;
  for (int it = 0; it < NI; ++it) {
    const size_t kt0 = (size_t)it << 7;
    const size_t k1 = kt0 + 64, k2 = kt0 + 128, k3 = kt0 + 192;
    const bool st = (it + 1 < NI);

    short8 aR[4], bR[NFRAG][2];

#define MFMA_PH(base, ks)                                                    \
    __builtin_amdgcn_s_setprio(1);                                          \
    _Pragma("unroll")                                                       \
    for (int i = 0; i < 4; ++i)                                             \
      _Pragma("unroll")                                                     \
      for (int f = 0; f < NFRAG; ++f)                                       \
        acc[(base) + i][f] = __builtin_amdgcn_mfma_f32_16x16x32_bf16(       \
            aR[i], bR[f][ks], acc[(base) + i][f], 0, 0, 0);                 \
    __builtin_amdgcn_s_setprio(0);

    // ---- ph1: (t0,lo,ks0); reads A + full B[t0]; stage Aq0[t1] ----
#pragma unroll
    for (int i = 0; i < 4; ++i) aR[i] = LDA(0, i, 0);
#pragma unroll
    for (int f = 0; f < NFRAG; ++f) { bR[f][0] = LDB(0, f, 0); bR[f][1] = LDB(0, f, 1); }
    SAq0(1, k1);
    BARRIER();
    LGKM0(); __builtin_amdgcn_sched_barrier(0);
    MFMA_PH(0, 0)
    BARRIER();

    // ---- ph2: (t0,hi,ks0); stage Aq1[t1] ----
#pragma unroll
    for (int i = 0; i < 4; ++i) aR[i] = LDA(0, 4 + i, 0);
    SAq1(1, k1);
    BARRIER();
    LGKM0(); __builtin_amdgcn_sched_barrier(0);
    MFMA_PH(4, 0)
    BARRIER();

    // ---- ph3: (t0,lo,ks1); stage B01[t2] ----
#pragma unroll
    for (int i = 0; i < 4; ++i) aR[i] = LDA(0, i, 1);
    if (st) SB01(0, k2);
    BARRIER();
    LGKM0(); __builtin_amdgcn_sched_barrier(0);
    MFMA_PH(0, 1)
    BARRIER();

    // ---- ph4: (t0,hi,ks1); stage B2[t2]; FORCE A[t1]+B[t1] ----
#pragma unroll
    for (int i = 0; i < 4; ++i) aR[i] = LDA(0, 4 + i, 1);
    if (st) { SB2(0, k2); VMCNT(4); } else { VMCNT(0); }
    BARRIER();
    LGKM0(); __builtin_amdgcn_sched_barrier(0);
    MFMA_PH(4, 1)
    BARRIER();

    // ---- ph5: (t1,lo,ks0); reads A + full B[t1]; stage Aq0[t2] ----
#pragma unroll
    for (int i = 0; i < 4; ++i) aR[i] = LDA(1, i, 0);
#pragma unroll
    for (int f = 0; f < NFRAG; ++f) { bR[f][0] = LDB(1, f, 0); bR[f][1] = LDB(1, f, 1); }
    if (st) SAq0(0, k2);
    BARRIER();
    LGKM0(); __builtin_amdgcn_sched_barrier(0);
    MFMA_PH(0, 0)
    BARRIER();

    // ---- ph6: (t1,hi,ks0); stage Aq1[t2] ----
#pragma unroll
    for (int i = 0; i < 4; ++i) aR[i] = LDA(1, 4 + i, 0);
    if (st) SAq1(0, k2);
    BARRIER();
    LGKM0(); __builtin_amdgcn_sched_barrier(0);
    MFMA_PH(4, 0)
    BARRIER();

    // ---- ph7: (t1,lo,ks1); stage B01[t3] ----
#pragma unroll
    for (int i = 0; i < 4; ++i) aR[i] = LDA(1, i, 1);
    if (st) SB01(1, k3);
    BARRIER();
    LGKM0(); __builtin_amdgcn_sched_barrier(0);
    MFMA_PH(0, 1)
    BARRIER();

    // ---- ph8: (t1,hi,ks1); stage B2[t3]; FORCE A[t2]+B[t2] ----
#pragma unroll
    for (int i = 0; i < 4; ++i) aR[i] = LDA(1, 4 + i, 1);
    if (st) { SB2(1, k3); VMCNT(4); } else { VMCNT(0); }
    BARRIER();
    LGKM0(); __builtin_amdgcn_sched_barrier(0);
    MFMA_PH(4, 1)
    BARRIER();

#undef MFMA_PH
  }
#undef LDA
#undef LDB

  const int r4 = (lane >> 4) << 2;
#pragma unroll
  for (int i = 0; i < 8; ++i) {
#pragma unroll
    for (int rr = 0; rr < 4; ++rr) {
      const size_t row = (size_t)(m0 + wm * 128 + i * 16 + r4 + rr);
#pragma unroll
      for (int f = 0; f < NFRAG; ++f) {
        const size_t col = (size_t)(n0 + wn * 16 * NFRAG + f * 16 + fr);
        if constexpr (OBF16)
          ((ushort_t*)Cp)[row * N + col] = f2bf(acc[i][f][rr]);
        else
          ((float*)Cp)[row * N + col] = acc[i][f][rr];
      }
    }
  }
}

// ---------------------------------------------------------------------------
// Flash attention, causal + ALiBi-sqrt (unchanged from R4/R5).
// ---------------------------------------------------------------------------
__global__ __launch_bounds__(256, 2)
void attn_fwd(const ushort_t* __restrict__ qkv,
              const ushort_t* __restrict__ vt,
              ushort_t* __restrict__ attn)
{
  __shared__ __align__(16) ushort_t Plds[4][32 * 40];

  const int bid = blockIdx.x;          // 512 blocks
  const int x   = bid & 7;
  const int p   = bid >> 3;
  const int j   = p & 15;
  const int g   = ((p >> 4) << 3) + x;
  const int b   = g >> 3;
  const int hkv = g & 7;

  const int tid  = threadIdx.x;
  const int wid  = tid >> 6, lane = tid & 63;
  const int h    = hkv * 4 + wid;
  const int fr   = lane & 15;
  const int kk8  = (lane >> 4) << 3;
  const int q4   = (lane >> 4) << 2;
  const float slope = exp2f(-0.25f * (float)(h + 1));
  const float scale = 0.08838834764831845f;

  const ushort_t* qp  = qkv + (size_t)b * Sc * QKVO + (size_t)h * Dc;
  const ushort_t* kp  = qkv + (size_t)b * Sc * QKVO + NHc * Dc + (size_t)hkv * Dc;
  const ushort_t* vtp = vt + (size_t)(b * NKVc + hkv) * Dc * Sc;
  ushort_t* myP = &Plds[wid][0];

  const floatx4 fz = {0.f, 0.f, 0.f, 0.f};

  auto process = [&](const int qb) {
    short8 qf[2][4];
#pragma unroll
    for (int t = 0; t < 2; ++t) {
      const int qrow = qb * 32 + t * 16 + fr;
#pragma unroll
      for (int s = 0; s < 4; ++s)
        qf[t][s] = *(const short8*)(qp + (size_t)qrow * QKVO + s * 32 + kk8);
    }

    floatx4 o[2][8];
#pragma unroll
    for (int t = 0; t < 2; ++t)
#pragma unroll
      for (int jj = 0; jj < 8; ++jj) o[t][jj] = fz;
    float mrow[2][4], lrow[2][4];
#pragma unroll
    for (int t = 0; t < 2; ++t)
#pragma unroll
      for (int rr = 0; rr < 4; ++rr) { mrow[t][rr] = -1e30f; lrow[t][rr] = 0.f; }

    for (int kb = 0; kb <= qb; ++kb) {
      floatx4 s_[2][2];
      s_[0][0] = fz; s_[0][1] = fz; s_[1][0] = fz; s_[1][1] = fz;
#pragma unroll
      for (int half = 0; half < 2; ++half) {
        const int kcol = kb * 32 + half * 16 + fr;
#pragma unroll
        for (int s = 0; s < 4; ++s) {
          const short8 kf = *(const short8*)(kp + (size_t)kcol * QKVO + s * 32 + kk8);
          s_[0][half] = __builtin_amdgcn_mfma_f32_16x16x32_bf16(qf[0][s], kf, s_[0][half], 0, 0, 0);
          s_[1][half] = __builtin_amdgcn_mfma_f32_16x16x32_bf16(qf[1][s], kf, s_[1][half], 0, 0, 0);
        }
      }

      short8 vf[8];
#pragma unroll
      for (int jj = 0; jj < 8; ++jj)
        vf[jj] = *(const short8*)(vtp + (size_t)(jj * 16 + fr) * Sc + kb * 32 + kk8);

#pragma unroll
      for (int t = 0; t < 2; ++t)
#pragma unroll
        for (int rr = 0; rr < 4; ++rr) {
          const int qg  = qb * 32 + t * 16 + q4 + rr;
          const int dk0 = qg - (kb * 32 + fr);
          const int dk1 = dk0 - 16;
          s_[t][0][rr] = (dk0 >= 0)
              ? s_[t][0][rr] * scale - slope * sqrtf((float)dk0) : -1e30f;
          s_[t][1][rr] = (dk1 >= 0)
              ? s_[t][1][rr] * scale - slope * sqrtf((float)dk1) : -1e30f;
        }

      float pmv[2][4];
#pragma unroll
      for (int t = 0; t < 2; ++t)
#pragma unroll
        for (int rr = 0; rr < 4; ++rr) {
          float pm = fmaxf(s_[t][0][rr], s_[t][1][rr]);
#pragma unroll
          for (int m = 1; m < 16; m <<= 1) pm = fmaxf(pm, __shfl_xor(pm, m));
          pmv[t][rr] = pm;
        }

      int need = 0;
#pragma unroll
      for (int t = 0; t < 2; ++t)
#pragma unroll
        for (int rr = 0; rr < 4; ++rr)
          need |= (pmv[t][rr] > mrow[t][rr] + 8.f) ? 1 : 0;
      if (__any(need)) {
#pragma unroll
        for (int t = 0; t < 2; ++t)
#pragma unroll
          for (int rr = 0; rr < 4; ++rr) {
            const float mnew = fmaxf(mrow[t][rr], pmv[t][rr]);
            const float corr = __expf(mrow[t][rr] - mnew);
            lrow[t][rr] *= corr;
            mrow[t][rr] = mnew;
#pragma unroll
            for (int jj = 0; jj < 8; ++jj) o[t][jj][rr] *= corr;
          }
      }

#pragma unroll
      for (int t = 0; t < 2; ++t)
#pragma unroll
        for (int rr = 0; rr < 4; ++rr) {
          const float p0 = __expf(s_[t][0][rr] - mrow[t][rr]);
          const float p1 = __expf(s_[t][1][rr] - mrow[t][rr]);
          lrow[t][rr] += p0 + p1;
          myP[(t * 16 + q4 + rr) * 40 + fr]      = f2bf(p0);
          myP[(t * 16 + q4 + rr) * 40 + 16 + fr] = f2bf(p1);
        }
      short8 pa[2];
      pa[0] = *(const short8*)&myP[fr * 40 + kk8];
      pa[1] = *(const short8*)&myP[(16 + fr) * 40 + kk8];

#pragma unroll
      for (int jj = 0; jj < 8; ++jj) {
        o[0][jj] = __builtin_amdgcn_mfma_f32_16x16x32_bf16(pa[0], vf[jj], o[0][jj], 0, 0, 0);
        o[1][jj] = __builtin_amdgcn_mfma_f32_16x16x32_bf16(pa[1], vf[jj], o[1][jj], 0, 0, 0);
      }
    }

#pragma unroll
    for (int t = 0; t < 2; ++t)
#pragma unroll
      for (int rr = 0; rr < 4; ++rr) {
        float rs = lrow[t][rr];
#pragma unroll
        for (int m = 1; m < 16; m <<= 1) rs += __shfl_xor(rs, m);
        const float inv = 1.f / rs;
        const size_t tok = (size_t)b * Sc + qb * 32 + t * 16 + q4 + rr;
#pragma unroll
        for (int jj = 0; jj < 8; ++jj)
          attn[tok * (size_t)(NHc * Dc) + h * Dc + jj * 16 + fr] = f2bf(o[t][jj][rr] * inv);
      }
  };

  process(31 - j);
  process(j);
}

// ---------------------------------------------------------------------------
extern "C" void kernel_launch(void* const* d_in, const int* in_sizes, int n_in,
                              void* d_out, int out_size, void* d_ws, size_t ws_size,
                              hipStream_t stream)
{
  const float* hidden = (const float*)d_in[0];
  const float* w_qkv  = (const float*)d_in[1];
  const float* w_o    = (const float*)d_in[2];
  float* out = (float*)d_out;

  // workspace layout (bf16 elems): 134.2 MB total
  ushort_t* wqT   = (ushort_t*)d_ws;                   // [6144][4096]  50.3MB
  ushort_t* hidb  = wqT + (size_t)QKVO * Hc;           // [4096][4096]  33.6MB
  ushort_t* qkvb  = hidb + (size_t)Mc * Hc;            // [4096][6144]  50.3MB
  ushort_t* attnb = hidb;                              // reuse after GEMM1
  ushort_t* woT   = wqT;                               // reuse after GEMM1
  ushort_t* vtb   = wqT + (size_t)Mc * Hc;             // reuse: wqT+33.6MB, 8.4MB

  // 1) hidden -> bf16
  cvt_bf16<<<dim3((Mc * Hc / 8) / 256), dim3(256), 0, stream>>>(
      hidden, hidb, Mc * Hc / 8);
  // 2) w_qkv^T -> bf16  [6144][4096]
  transpose_cvt<<<dim3((Hc / 64) * (QKVO / 64)), dim3(256), 0, stream>>>(
      w_qkv, wqT, Hc, QKVO);
  // 3) qkv = hidden @ w_qkv   (interleaved deep, 256x192 -> 512 blocks)
  gemm_nt8d<3, true><<<dim3((Mc / 256) * (QKVO / 192)), dim3(512), 0, stream>>>(
      hidb, wqT, qkvb, Mc, QKVO, Hc);
  // 4) V -> VT  [b][hkv][d][s]
  v_transpose<<<dim3(1024), dim3(256), 0, stream>>>(qkvb, vtb);
  // 5) attention
  attn_fwd<<<dim3(512), dim3(256), 0, stream>>>(qkvb, vtb, attnb);
  // 6) w_o^T -> bf16  [4096][4096]
  transpose_cvt<<<dim3((Hc / 64) * (Hc / 64)), dim3(256), 0, stream>>>(
      w_o, woT, Hc, Hc);
  // 7) out = attn @ w_o       (sequential deep, 256x256 -> 256 blocks)
  gemm_nt8s<4, false><<<dim3((Mc / 256) * (Hc / 256)), dim3(512), 0, stream>>>(
      attnb, woT, out, Mc, Hc, Hc);
}